// Round 10
// baseline (341.435 us; speedup 1.0000x reference)
//
#include <hip/hip_runtime.h>
#include <hip/hip_fp16.h>

// FastMultiTaskGP: FFT(65536) of 136 upper-tri k1 rows + 16 y rows (ortho),
// per-frequency 16x16 Schur-complement inversion (Hermitian), logdet + quad,
// write A.re / A.im (134 MB) + 2 scalars.
//
// Conjugate symmetry: real inputs => A(N-f)=conj(A(f)); invert f=0..32768,
// mirror-write the rest in-kernel, weight logdet/quad by 2 for 0<f<32768.
// Inversion: 4 lanes per frequency (DPP quad_perm Tm exchange -- zero LDS in
// the serial chain), 32 freqs per 128-thread block, lam in LDS as fp16
// [entry][freq] (21.5 KB), launch_bounds(128,2) so the 128-VGPR A-tile does
// NOT spill (r5's mistake). Grid 1025 = 4 blocks/CU exactly.

#define TT 16
#define NF 65536
#define NPAIR 136
#define NROWS 152
#define NHALF 32768
#define FPB 32

static const size_t AIMAG  = 16777216;   // 16*16*65536
static const size_t OUT_LD = 33554432;
static const size_t OUT_QD = 33554433;

typedef float2 c32;

__device__ __forceinline__ c32 cmul(c32 a, c32 b) { return make_float2(a.x*b.x - a.y*b.y, a.x*b.y + a.y*b.x); }
__device__ __forceinline__ c32 cadd(c32 a, c32 b) { return make_float2(a.x + b.x, a.y + b.y); }
__device__ __forceinline__ c32 csub(c32 a, c32 b) { return make_float2(a.x - b.x, a.y - b.y); }

// DPP helpers (ctrl must be a literal/ICE at each use site)
#define DPPF(x, ctrl) __int_as_float(__builtin_amdgcn_update_dpp( \
    __float_as_int(x), __float_as_int(x), (ctrl), 0xF, 0xF, false))
// quad xor1 = 0xB1 ; quad xor2 = 0x4E ; bcast lane q = 0x55*q

__constant__ c32 W16[16] = {
  { 1.0f, 0.0f}, { 0.92387953f,-0.38268343f}, { 0.70710678f,-0.70710678f}, { 0.38268343f,-0.92387953f},
  { 0.0f,-1.0f}, {-0.38268343f,-0.92387953f}, {-0.70710678f,-0.70710678f}, {-0.92387953f,-0.38268343f},
  {-1.0f, 0.0f}, {-0.92387953f, 0.38268343f}, {-0.70710678f, 0.70710678f}, {-0.38268343f, 0.92387953f},
  { 0.0f, 1.0f}, { 0.38268343f, 0.92387953f}, { 0.70710678f, 0.70710678f}, { 0.92387953f, 0.38268343f}
};

__device__ __forceinline__ void dft4(c32 a0, c32 a1, c32 a2, c32 a3,
                                     c32& c0, c32& c1, c32& c2, c32& c3) {
  c32 s0 = cadd(a0, a2), s1 = csub(a0, a2);
  c32 s2 = cadd(a1, a3), s3 = csub(a1, a3);
  c0 = cadd(s0, s2);
  c2 = csub(s0, s2);
  c1 = make_float2(s1.x + s3.y, s1.y - s3.x);
  c3 = make_float2(s1.x - s3.y, s1.y + s3.x);
}

__device__ __forceinline__ void dft16(c32 v[16]) {
  c32 t[16];
  #pragma unroll
  for (int p = 0; p < 4; ++p) {
    c32 c0, c1, c2, c3;
    dft4(v[p], v[p+4], v[p+8], v[p+12], c0, c1, c2, c3);
    t[4*p+0] = c0;
    t[4*p+1] = cmul(c1, W16[p]);
    t[4*p+2] = cmul(c2, W16[(2*p) & 15]);
    t[4*p+3] = cmul(c3, W16[(3*p) & 15]);
  }
  #pragma unroll
  for (int q = 0; q < 4; ++q) {
    c32 c0, c1, c2, c3;
    dft4(t[q], t[q+4], t[q+8], t[q+12], c0, c1, c2, c3);
    v[q+0]  = c0;
    v[q+4]  = c1;
    v[q+8]  = c2;
    v[q+12] = c3;
  }
}

__global__ __launch_bounds__(256) void fft_pass1(const float* __restrict__ k1,
                                                 const float* __restrict__ y,
                                                 c32* __restrict__ out) {
  const int row = blockIdx.y;
  const float* src;
  float scale = 1.0f;
  if (row < NPAIR) {
    int i = 0, rem = row;
    while (rem >= TT - i) { rem -= TT - i; ++i; }
    int j = i + rem;
    src = k1 + (size_t)(i * TT + j) * NF;
  } else {
    src = y + (size_t)(row - NPAIR) * NF;
    scale = 1.0f / 256.0f;   // ortho norm
  }
  const int p = blockIdx.x * 256 + threadIdx.x;   // [0,4096)
  c32 v[16];
  #pragma unroll
  for (int i = 0; i < 16; ++i) v[i] = make_float2(src[p + 4096*i] * scale, 0.0f);
  dft16(v);
  float sa, ca;
  __sincosf(-6.2831853071795865f * (float)p / 65536.0f, &sa, &ca);
  c32 w1 = make_float2(ca, sa);
  c32 wj = w1;
  c32* dst = out + (size_t)row * NF + 16 * p;
  dst[0] = v[0];
  #pragma unroll
  for (int j = 1; j < 16; ++j) { dst[j] = cmul(v[j], wj); wj = cmul(wj, w1); }
}

// Stockham radix-16 pass: length NN, stride S. TRIM: last pass stores j<=8
// (covers all f < 36864 that invert reads).
template<int NN, int S, bool TRIM>
__global__ __launch_bounds__(256) void fft_pass(const c32* __restrict__ in,
                                                c32* __restrict__ out) {
  const int w = blockIdx.x * 256 + threadIdx.x;   // [0,4096)
  const int q = w & (S - 1);
  const int p = w / S;
  const size_t rbase = (size_t)blockIdx.y * NF;
  c32 v[16];
  #pragma unroll
  for (int i = 0; i < 16; ++i) v[i] = in[rbase + w + 4096*i];
  dft16(v);
  if constexpr (NN > 16) {
    float sa, ca;
    __sincosf(-6.2831853071795865f * (float)p / (float)NN, &sa, &ca);
    c32 w1 = make_float2(ca, sa);
    c32 wj = w1;
    #pragma unroll
    for (int j = 1; j < 16; ++j) { v[j] = cmul(v[j], wj); wj = cmul(wj, w1); }
  }
  c32* dst = out + rbase + q + (size_t)S * 16 * p;
  #pragma unroll
  for (int j = 0; j < 16; ++j) {
    if (!TRIM || j <= 8) dst[(size_t)S * j] = v[j];
  }
}

__global__ void init_out(float* __restrict__ out) {
  if (threadIdx.x == 0 && blockIdx.x == 0) {
    out[OUT_LD] = 0.0f;
    out[OUT_QD] = 0.0f;
  }
}

// ---- Schur step L (compile-time), 4 lanes/freq, lane owns rows 4g..4g+3 ----
// lamf: &lam[0][fi], element stride FPB half2. Tm exchange via DPP quad_perm.
#define UPDATE_J(J)                                                          \
  if constexpr ((J) < L) {                                                   \
    float tjr = DPPF(tr[(J)&3], 0x55*((J)>>2));                              \
    float tji = DPPF(ti[(J)&3], 0x55*((J)>>2));                              \
    _Pragma("unroll")                                                        \
    for (int m = 0; m < 4; ++m) {                                            \
      Ar[m][(J)] = mf[m]*Ar[m][(J)] + cr[m]*tjr + ci[m]*tji;                 \
      Ai[m][(J)] = mf[m]*Ai[m][(J)] + ci[m]*tjr - cr[m]*tji;                 \
    }                                                                        \
  }

template<int L>
__device__ __forceinline__ void schur_step(const __half2* __restrict__ lamf,
                                           float (&Ar)[4][16], float (&Ai)[4][16],
                                           const int (&row)[4], const int (&ro)[4],
                                           float& ld) {
  float tr[4] = {0.f,0.f,0.f,0.f}, ti[4] = {0.f,0.f,0.f,0.f};
  #pragma unroll
  for (int k = 0; k < L; ++k) {
    c32 B = __half22float2(lamf[((((k*(31-k))>>1) + L)) * FPB]);  // quad-bcast
    #pragma unroll
    for (int m = 0; m < 4; ++m) {
      tr[m] += Ar[m][k]*B.x - Ai[m][k]*B.y;
      ti[m] += Ar[m][k]*B.y + Ai[m][k]*B.x;
    }
  }
  // partial M over own rows (rows >= L have Tm = 0; garbage B harmless/finite)
  float mr = 0.f, mi = 0.f;
  #pragma unroll
  for (int m = 0; m < 4; ++m) {
    c32 Bo = __half22float2(lamf[(ro[m] + L) * FPB]);
    mr += Bo.x*tr[m] + Bo.y*ti[m];
    mi += Bo.x*ti[m] - Bo.y*tr[m];
  }
  // quad xor-reduce -> all 4 lanes hold full M
  mr += DPPF(mr, 0xB1); mi += DPPF(mi, 0xB1);
  mr += DPPF(mr, 0x4E); mi += DPPF(mi, 0x4E);

  c32 ll = __half22float2(lamf[((((L*(31-L))>>1) + L)) * FPB]);
  float Sr = ll.x - mr, Si = ll.y - mi;
  float s2 = Sr*Sr + Si*Si;
  ld += 0.5f * __logf(s2);
  float is2 = 1.0f / s2;
  float vr = Sr * is2, vi = -Si * is2;         // Sinv

  float pr[4], pi[4], cr[4], ci[4], mf[4];
  #pragma unroll
  for (int m = 0; m < 4; ++m) {
    pr[m] = tr[m]*vr - ti[m]*vi;               // P (0 for rows > L)
    pi[m] = tr[m]*vi + ti[m]*vr;
    bool diag = (row[m] == L);
    cr[m] = diag ? -vr : pr[m];
    ci[m] = diag ?  vi : pi[m];
    mf[m] = diag ? 0.0f : 1.0f;
  }
  UPDATE_J(0)  UPDATE_J(1)  UPDATE_J(2)  UPDATE_J(3)
  UPDATE_J(4)  UPDATE_J(5)  UPDATE_J(6)  UPDATE_J(7)
  UPDATE_J(8)  UPDATE_J(9)  UPDATE_J(10) UPDATE_J(11)
  UPDATE_J(12) UPDATE_J(13) UPDATE_J(14) UPDATE_J(15)
  #pragma unroll
  for (int m = 0; m < 4; ++m) {
    bool diag = (row[m] == L);
    Ar[m][L] = diag ? vr : -pr[m];
    Ai[m][L] = diag ? vi : -pi[m];
  }
}

__global__ __launch_bounds__(128, 2) void invert_write(const c32* __restrict__ spec,
                                                       float* __restrict__ out) {
  __shared__ union {
    struct {
      __half2 lam[NPAIR][FPB];   // [packed entry][freq] 17408 B
      c32 yts[TT][FPB];          // [task][freq]          4096 B
    } rec;                       // 21504 B
    float plane[FPB][65];        //  8320 B
  } sh;
  __shared__ float redl[2], redq[2];

  // bijective XCD-chunked swizzle
  const int nwg  = gridDim.x;           // 1025
  const int orig = blockIdx.x;
  const int xcd  = orig & 7;
  const int pos  = orig >> 3;
  const int qq   = nwg >> 3, rm = nwg & 7;
  const int chunk = (xcd < rm ? xcd * (qq + 1) : rm * (qq + 1) + (xcd - rm) * qq) + pos;

  const int t  = threadIdx.x;
  const int fi = t >> 2;            // freq within block [0,32)
  const int g  = t & 3;             // quad lane = row group
  const int f0 = chunk * FPB;
  const int f  = f0 + fi;

  for (int idx = t; idx < NPAIR * FPB; idx += 128) {
    int rowi = idx >> 5, ff = idx & 31;
    sh.rec.lam[rowi][ff] = __float22half2_rn(spec[(size_t)rowi * NF + f0 + ff]);
  }
  for (int idx = NPAIR * FPB + t; idx < NROWS * FPB; idx += 128) {
    int rowi = idx >> 5, ff = idx & 31;
    sh.rec.yts[rowi - NPAIR][ff] = spec[(size_t)rowi * NF + f0 + ff];
  }
  __syncthreads();

  int row[4], ro[4];
  #pragma unroll
  for (int m = 0; m < 4; ++m) {
    row[m] = 4*g + m;
    ro[m]  = (row[m] * (31 - row[m])) >> 1;
  }

  const __half2* lamf = &sh.rec.lam[0][fi];
  const c32*     ytf  = &sh.rec.yts[0][fi];

  float Ar[4][16], Ai[4][16];
  #pragma unroll
  for (int m = 0; m < 4; ++m)
    #pragma unroll
    for (int j = 0; j < 16; ++j) { Ar[m][j] = 0.0f; Ai[m][j] = 0.0f; }

  c32 l00 = __half22float2(lamf[0]);
  float m00 = l00.x*l00.x + l00.y*l00.y;
  float im00 = 1.0f / m00;
  float ld = 0.5f * __logf(m00);
  if (row[0] == 0) {                 // only lane g==0 owns row 0
    Ar[0][0] =  l00.x * im00;
    Ai[0][0] = -l00.y * im00;
  }

  schur_step< 1>(lamf, Ar, Ai, row, ro, ld);
  schur_step< 2>(lamf, Ar, Ai, row, ro, ld);
  schur_step< 3>(lamf, Ar, Ai, row, ro, ld);
  schur_step< 4>(lamf, Ar, Ai, row, ro, ld);
  schur_step< 5>(lamf, Ar, Ai, row, ro, ld);
  schur_step< 6>(lamf, Ar, Ai, row, ro, ld);
  schur_step< 7>(lamf, Ar, Ai, row, ro, ld);
  schur_step< 8>(lamf, Ar, Ai, row, ro, ld);
  schur_step< 9>(lamf, Ar, Ai, row, ro, ld);
  schur_step<10>(lamf, Ar, Ai, row, ro, ld);
  schur_step<11>(lamf, Ar, Ai, row, ro, ld);
  schur_step<12>(lamf, Ar, Ai, row, ro, ld);
  schur_step<13>(lamf, Ar, Ai, row, ro, ld);
  schur_step<14>(lamf, Ar, Ai, row, ro, ld);
  schur_step<15>(lamf, Ar, Ai, row, ro, ld);

  // quad: qd partial over own rows, then quad-reduce
  float qd = 0.0f;
  #pragma unroll
  for (int m = 0; m < 4; ++m) {
    float sr = 0.f, si = 0.f;
    #pragma unroll
    for (int j = 0; j < 16; ++j) {
      c32 yj = ytf[j * FPB];
      sr += Ar[m][j]*yj.x - Ai[m][j]*yj.y;
      si += Ar[m][j]*yj.y + Ai[m][j]*yj.x;
    }
    c32 yo = ytf[row[m] * FPB];
    qd += yo.x*sr + yo.y*si;
  }
  qd += DPPF(qd, 0xB1);
  qd += DPPF(qd, 0x4E);

  float w  = (f == 0 || f == NHALF) ? 1.0f : (f < NHALF ? 2.0f : 0.0f);
  float lw = (g == 0) ? ld * w : 0.0f;
  float qw = (g == 0) ? qd * w : 0.0f;

  #pragma unroll
  for (int d = 1; d < 64; d <<= 1) {
    lw += __shfl_xor(lw, d, 64);
    qw += __shfl_xor(qw, d, 64);
  }
  if ((t & 63) == 0) { redl[t >> 6] = lw; redq[t >> 6] = qw; }
  __syncthreads();   // recursion LDS reads complete before plane reuse
  if (t == 0) {
    atomicAdd(out + OUT_LD, redl[0] + redl[1]);
    atomicAdd(out + OUT_QD, redq[0] + redq[1]);
  }

  // ---- stores via 8-phase LDS plane: full-line dir + mirror ----
  const int fl = t & 31;            // frequency offset within block
  const int w2 = t >> 5;            // row-cluster quarter [0,4)
  const int fL = f0 + fl;
  const bool dok = (fL <= NHALF);
  const bool mok = (fL > 0 && fL < NHALF);
  const size_t fD = (size_t)fL;
  const size_t fM = (size_t)(NF - fL);

  #pragma unroll
  for (int m = 0; m < 4; ++m) {
    // RE phase: plane[fi][g*16+j] = A[4g+m][j]
    #pragma unroll
    for (int j = 0; j < 16; ++j) sh.plane[fi][g * 16 + j] = Ar[m][j];
    __syncthreads();
    #pragma unroll
    for (int u = 0; u < 16; ++u) {
      float v = sh.plane[fl][w2 * 16 + u];
      size_t o = (size_t)((4 * w2 + m) * 16 + u) * NF;
      if (dok) __builtin_nontemporal_store(v, &out[o + fD]);
      if (mok) __builtin_nontemporal_store(v, &out[o + fM]);
    }
    __syncthreads();
    // IM phase
    #pragma unroll
    for (int j = 0; j < 16; ++j) sh.plane[fi][g * 16 + j] = Ai[m][j];
    __syncthreads();
    #pragma unroll
    for (int u = 0; u < 16; ++u) {
      float v = sh.plane[fl][w2 * 16 + u];
      size_t o = AIMAG + (size_t)((4 * w2 + m) * 16 + u) * NF;
      if (dok) __builtin_nontemporal_store(v, &out[o + fD]);
      if (mok) __builtin_nontemporal_store(-v, &out[o + fM]);
    }
    __syncthreads();
  }
}

extern "C" void kernel_launch(void* const* d_in, const int* in_sizes, int n_in,
                              void* d_out, int out_size, void* d_ws, size_t ws_size,
                              hipStream_t stream) {
  const float* k1 = (const float*)d_in[0];
  const float* y  = (const float*)d_in[1];
  float* out = (float*)d_out;
  c32* scratch = (c32*)d_out;   // 79.7 MB < 134 MB out buffer, overwritten later
  c32* spec    = (c32*)d_ws;    // 76 MiB workspace

  dim3 grid(16, NROWS);
  dim3 blk(256);

  fft_pass1                <<<grid, blk, 0, stream>>>(k1, y, scratch);
  fft_pass<4096, 16, false><<<grid, blk, 0, stream>>>(scratch, spec);
  fft_pass<256, 256, false><<<grid, blk, 0, stream>>>(spec, scratch);
  fft_pass<16, 4096, true> <<<grid, blk, 0, stream>>>(scratch, spec);

  init_out<<<1, 64, 0, stream>>>(out);
  invert_write<<<1025, dim3(128), 0, stream>>>(spec, out);   // f = 0..32768 (+tail)
}

// Round 11
// 142.019 us; speedup vs baseline: 2.4041x; 2.4041x over previous
//
#include <hip/hip_runtime.h>
#include <hip/hip_fp16.h>

// FastMultiTaskGP: FFT(65536) of 136 upper-tri k1 rows + 16 y rows (ortho),
// per-frequency 16x16 Schur-complement inversion (Hermitian), logdet + quad,
// write A.re / A.im (134 MB) + 2 scalars.
//
// FFT: four-step 256x256. Kernel A: column FFTs (stride 256) in LDS + outer
// twiddle -> spec1[row][k1][n2]. Kernel B: row FFTs over n2 in LDS, write
// X[f=256*k2+k1] transposed from registers (natural-f order, 128B segments),
// trimmed to k2<=128 (invert only reads f<=32783). Total FFT traffic 565->240MB.
// Inversion (r8): conj symmetry (invert f=0..32768, mirror-write, weight 2),
// 16 lanes/freq, fp16 lam in LDS, LDS tmb exchange, rotated store-plane.

#define TT 16
#define NF 65536
#define NPAIR 136
#define NROWS 152
#define NHALF 32768

static const size_t AIMAG  = 16777216;   // 16*16*65536
static const size_t OUT_LD = 33554432;
static const size_t OUT_QD = 33554433;

typedef float2 c32;

__device__ __forceinline__ c32 cmul(c32 a, c32 b) { return make_float2(a.x*b.x - a.y*b.y, a.x*b.y + a.y*b.x); }
__device__ __forceinline__ c32 cadd(c32 a, c32 b) { return make_float2(a.x + b.x, a.y + b.y); }
__device__ __forceinline__ c32 csub(c32 a, c32 b) { return make_float2(a.x - b.x, a.y - b.y); }

__constant__ c32 W16[16] = {
  { 1.0f, 0.0f}, { 0.92387953f,-0.38268343f}, { 0.70710678f,-0.70710678f}, { 0.38268343f,-0.92387953f},
  { 0.0f,-1.0f}, {-0.38268343f,-0.92387953f}, {-0.70710678f,-0.70710678f}, {-0.92387953f,-0.38268343f},
  {-1.0f, 0.0f}, {-0.92387953f, 0.38268343f}, {-0.70710678f, 0.70710678f}, {-0.38268343f, 0.92387953f},
  { 0.0f, 1.0f}, { 0.38268343f, 0.92387953f}, { 0.70710678f, 0.70710678f}, { 0.92387953f, 0.38268343f}
};

__device__ __forceinline__ void dft4(c32 a0, c32 a1, c32 a2, c32 a3,
                                     c32& c0, c32& c1, c32& c2, c32& c3) {
  c32 s0 = cadd(a0, a2), s1 = csub(a0, a2);
  c32 s2 = cadd(a1, a3), s3 = csub(a1, a3);
  c0 = cadd(s0, s2);
  c2 = csub(s0, s2);
  c1 = make_float2(s1.x + s3.y, s1.y - s3.x);
  c3 = make_float2(s1.x - s3.y, s1.y + s3.x);
}

__device__ __forceinline__ void dft16(c32 v[16]) {
  c32 t[16];
  #pragma unroll
  for (int p = 0; p < 4; ++p) {
    c32 c0, c1, c2, c3;
    dft4(v[p], v[p+4], v[p+8], v[p+12], c0, c1, c2, c3);
    t[4*p+0] = c0;
    t[4*p+1] = cmul(c1, W16[p]);
    t[4*p+2] = cmul(c2, W16[(2*p) & 15]);
    t[4*p+3] = cmul(c3, W16[(3*p) & 15]);
  }
  #pragma unroll
  for (int q = 0; q < 4; ++q) {
    c32 c0, c1, c2, c3;
    dft4(t[q], t[q+4], t[q+8], t[q+12], c0, c1, c2, c3);
    v[q+0]  = c0;
    v[q+4]  = c1;
    v[q+8]  = c2;
    v[q+12] = c3;
  }
}

// ---- Kernel A: inner 256-FFT over n1 (stride 256) + outer twiddle ----
// x[n]=x[n1*256+n2]; G[k1][n2] = FFT_n1 * W_65536^{n2 k1}; out [row][k1][n2].
// Block = 16 n2-columns x 16 butterfly threads; two radix-16 passes via LDS.
__global__ __launch_bounds__(256) void fftA(const float* __restrict__ k1,
                                            const float* __restrict__ y,
                                            c32* __restrict__ out) {
  __shared__ c32 buf[16][258];
  const int t = threadIdx.x;
  const int c = t & 15;                 // column within tile
  const int w = t >> 4;                 // butterfly thread
  const int n2 = (blockIdx.x << 4) + c;
  const int row = blockIdx.y;
  const float* src;
  float scale = 1.0f;
  if (row < NPAIR) {
    int i = 0, rem = row;
    while (rem >= TT - i) { rem -= TT - i; ++i; }
    int j = i + rem;
    src = k1 + (size_t)(i * TT + j) * NF;
  } else {
    src = y + (size_t)(row - NPAIR) * NF;
    scale = 1.0f / 256.0f;   // ortho norm
  }
  // pass 1 (NN=256,S=1): read x[(w+16i)*256+n2], dft16, twiddle W_256^{w j}
  c32 v[16];
  #pragma unroll
  for (int i = 0; i < 16; ++i)
    v[i] = make_float2(src[(w + 16*i) * 256 + n2] * scale, 0.0f);
  dft16(v);
  {
    float sa, ca;
    __sincosf(-6.2831853071795865f * (float)w / 256.0f, &sa, &ca);
    c32 w1 = make_float2(ca, sa), wj = w1;
    #pragma unroll
    for (int j = 1; j < 16; ++j) { v[j] = cmul(v[j], wj); wj = cmul(wj, w1); }
  }
  #pragma unroll
  for (int j = 0; j < 16; ++j) buf[c][16*w + j] = v[j];
  __syncthreads();
  // pass 2 (NN=16,S=16): read [w+16i]; k1 = w+16j; outer twiddle; store
  c32 u[16];
  #pragma unroll
  for (int i = 0; i < 16; ++i) u[i] = buf[c][w + 16*i];
  dft16(u);
  float sa, ca;
  __sincosf(-6.2831853071795865f * (float)(n2 * w) / 65536.0f, &sa, &ca);
  c32 tw = make_float2(ca, sa);
  __sincosf(-6.2831853071795865f * (float)n2 / 4096.0f, &sa, &ca);
  c32 st = make_float2(ca, sa);       // step for k1 += 16
  c32* dst = out + (size_t)row * NF + n2;
  #pragma unroll
  for (int j = 0; j < 16; ++j) {
    dst[(size_t)(w + 16*j) << 8] = cmul(u[j], tw);
    tw = cmul(tw, st);
  }
}

// ---- Kernel B: 256-FFT over n2 (contiguous), transposed trimmed output ----
// in [row][k1][n2] -> X[f = 256 k2 + k1] at [row][f], only k2 <= 128.
__global__ __launch_bounds__(256) void fftB(const c32* __restrict__ in,
                                            c32* __restrict__ out) {
  __shared__ c32 buf[16][258];
  const int t = threadIdx.x;
  const int c = t & 15;                 // local k1
  const int w = t >> 4;
  const int c0 = blockIdx.x << 4;
  const int row = blockIdx.y;
  const c32* src = in + (size_t)row * NF + ((size_t)c0 << 8);
  #pragma unroll
  for (int it = 0; it < 16; ++it) buf[it][t] = src[(it << 8) + t];
  __syncthreads();
  // pass 1: read staged, twiddle, write back (read-all THEN write: barrier)
  c32 v[16];
  #pragma unroll
  for (int i = 0; i < 16; ++i) v[i] = buf[c][w + 16*i];
  dft16(v);
  {
    float sa, ca;
    __sincosf(-6.2831853071795865f * (float)w / 256.0f, &sa, &ca);
    c32 w1 = make_float2(ca, sa), wj = w1;
    #pragma unroll
    for (int j = 1; j < 16; ++j) { v[j] = cmul(v[j], wj); wj = cmul(wj, w1); }
  }
  __syncthreads();
  #pragma unroll
  for (int j = 0; j < 16; ++j) buf[c][16*w + j] = v[j];
  __syncthreads();
  // pass 2: result in regs, write transposed: f = 256 k2 + c0 + c
  c32 u[16];
  #pragma unroll
  for (int i = 0; i < 16; ++i) u[i] = buf[c][w + 16*i];
  dft16(u);
  c32* dst = out + (size_t)row * NF + c0 + c;
  #pragma unroll
  for (int j = 0; j < 16; ++j) {
    int k2 = w + 16*j;
    if (k2 <= 128) dst[(size_t)k2 << 8] = u[j];
  }
}

__global__ void init_out(float* __restrict__ out) {
  if (threadIdx.x == 0 && blockIdx.x == 0) {
    out[OUT_LD] = 0.0f;
    out[OUT_QD] = 0.0f;
  }
}

// 16 lanes per frequency (lane = row r). l-loop fully unrolled, branch-free
// uniform update, LDS tmb exchange (wave-synchronous). lam in fp16 half2.
// Store plane uses rotation swizzle (conflict-free writes AND reads).
__global__ __launch_bounds__(256) void invert_write(const c32* __restrict__ spec,
                                                    float* __restrict__ out) {
  __shared__ union {
    struct {
      __half2 lam[NPAIR][16];   // [packed entry][freq]  8704 B
      c32 yts[16][17];          //  2176 B
      float4 tmb[16][17];       //  4352 B
    } rec;                      // 15232 B
    float plane[16][260];       // 16640 B
  } sh;
  __shared__ float redl[4], redq[4];

  // bijective XCD-chunked swizzle
  const int nwg  = gridDim.x;           // 2049
  const int orig = blockIdx.x;
  const int xcd  = orig & 7;
  const int pos  = orig >> 3;
  const int qq   = nwg >> 3, rm = nwg & 7;
  const int chunk = (xcd < rm ? xcd * (qq + 1) : rm * (qq + 1) + (xcd - rm) * qq) + pos;

  const int t  = threadIdx.x;
  const int fi = t >> 4;
  const int r  = t & 15;
  const int f0 = chunk << 4;
  const int f  = f0 + fi;

  for (int idx = t; idx < NPAIR * 16; idx += 256) {
    int rowi = idx >> 4, ff = idx & 15;
    c32 val = spec[(size_t)rowi * NF + f0 + ff];
    sh.rec.lam[rowi][ff] = __float22half2_rn(val);
  }
  for (int idx = NPAIR * 16 + t; idx < NROWS * 16; idx += 256) {
    int rowi = idx >> 4, ff = idx & 15;
    sh.rec.yts[ff][rowi - NPAIR] = spec[(size_t)rowi * NF + f0 + ff];
  }
  __syncthreads();

  const int rowoff = (r * (31 - r)) >> 1;   // pidx(r,l) = rowoff + l

  float Ar[16], Ai[16];
  #pragma unroll
  for (int k = 0; k < 16; ++k) { Ar[k] = 0.0f; Ai[k] = 0.0f; }

  c32 l00 = __half22float2(sh.rec.lam[0][fi]);
  float m00 = l00.x*l00.x + l00.y*l00.y;
  float im00 = 1.0f / m00;
  float ld = 0.5f * __logf(m00);            // uniform across group, masked at reduce
  bool r0 = (r == 0);
  Ar[0] = r0 ?  l00.x * im00 : 0.0f;
  Ai[0] = r0 ? -l00.y * im00 : 0.0f;

  #pragma unroll
  for (int l = 1; l < TT; ++l) {
    // Tm[r] = sum_{k<l} A[r][k] * B[k]
    float tr = 0.0f, ti = 0.0f;
    #pragma unroll
    for (int k = 0; k < l; ++k) {
      c32 B = __half22float2(sh.rec.lam[((k * (31 - k)) >> 1) + l][fi]);
      tr += Ar[k]*B.x - Ai[k]*B.y;
      ti += Ar[k]*B.y + Ai[k]*B.x;
    }
    c32 Bo = __half22float2(sh.rec.lam[rowoff + l][fi]);
    float cbr = Bo.x*tr + Bo.y*ti;
    float cbi = Bo.x*ti - Bo.y*tr;
    sh.rec.tmb[fi][r] = make_float4(tr, ti, cbr, cbi);   // same wave: in-order DS

    float tjr[TT], tji[TT];
    float mr = 0.0f, mi = 0.0f;
    #pragma unroll
    for (int j = 0; j < l; ++j) {
      float4 q = sh.rec.tmb[fi][j];
      tjr[j] = q.x; tji[j] = q.y;
      mr += q.z;    mi += q.w;
    }

    c32 ll = __half22float2(sh.rec.lam[((l * (31 - l)) >> 1) + l][fi]);
    float Sr = ll.x - mr, Si = ll.y - mi;
    float s2 = Sr*Sr + Si*Si;
    ld += 0.5f * __logf(s2);
    float is2 = 1.0f / s2;
    float vr =  Sr * is2;                    // Sinv
    float vi = -Si * is2;
    float pr = tr*vr - ti*vi;                // P[r] (0 for r>l)
    float pi = tr*vi + ti*vr;

    bool diag = (r == l);
    float cr = diag ? -vr : pr;
    float ci = diag ?  vi : pi;
    float m  = diag ? 0.0f : 1.0f;

    #pragma unroll
    for (int j = 0; j < l; ++j) {
      Ar[j] = m*Ar[j] + cr*tjr[j] + ci*tji[j];
      Ai[j] = m*Ai[j] + ci*tjr[j] - cr*tji[j];
    }
    Ar[l] = diag ? vr : -pr;
    Ai[l] = diag ? vi : -pi;
  }

  // weights: f=0 / f=32768 once; 0<f<32768 twice; f>32768 excluded
  float w = (f == 0 || f == NHALF) ? 1.0f : (f < NHALF ? 2.0f : 0.0f);

  // quad: Re( conj(yt[r]) * sum_j A[r][j] yt[j] )
  float sr = 0.0f, si = 0.0f;
  #pragma unroll
  for (int j = 0; j < 16; ++j) {
    c32 yj = sh.rec.yts[fi][j];
    sr += Ar[j]*yj.x - Ai[j]*yj.y;
    si += Ar[j]*yj.y + Ai[j]*yj.x;
  }
  c32 yr = sh.rec.yts[fi][r];
  float qd = (yr.x*sr + yr.y*si) * w;
  float lw = r0 ? ld * w : 0.0f;

  #pragma unroll
  for (int d = 1; d < 64; d <<= 1) {
    lw += __shfl_xor(lw, d, 64);
    qd += __shfl_xor(qd, d, 64);
  }
  if ((t & 63) == 0) { redl[t >> 6] = lw; redq[t >> 6] = qd; }
  __syncthreads();   // all recursion LDS reads complete before plane reuse
  if (t == 0) {
    atomicAdd(out + OUT_LD, redl[0] + redl[1] + redl[2] + redl[3]);
    atomicAdd(out + OUT_QD, redq[0] + redq[1] + redq[2] + redq[3]);
  }

  // ---- coalesced store via rotated LDS plane ----
  // value A[r][j] stored at plane[fi][r*16 + ((j+r)&15)] : write banks
  // (17r + j) mod 32 distinct across lanes; reads 2-way broadcast (free).
  const int lf = t & 15;            // frequency offset within block
  const int cl = t >> 4;            // row cluster
  const int fL = f0 + lf;
  const bool dir_ok = (fL <= NHALF);
  const bool mir_ok = (fL > 0 && fL < NHALF);
  const size_t fD = (size_t)fL;
  const size_t fM = (size_t)(NF - fL);

  // RE plane
  #pragma unroll
  for (int j = 0; j < 16; ++j) sh.plane[fi][r * 16 + ((j + r) & 15)] = Ar[j];
  __syncthreads();
  #pragma unroll
  for (int u = 0; u < 16; ++u) {
    int rr = u * 16 + cl;
    float v = sh.plane[lf][u * 16 + ((cl + u) & 15)];
    size_t o = (size_t)rr * NF;
    if (dir_ok) out[o + fD] = v;
    if (mir_ok) out[o + fM] = v;
  }
  __syncthreads();
  // IM plane
  #pragma unroll
  for (int j = 0; j < 16; ++j) sh.plane[fi][r * 16 + ((j + r) & 15)] = Ai[j];
  __syncthreads();
  #pragma unroll
  for (int u = 0; u < 16; ++u) {
    int rr = u * 16 + cl;
    float v = sh.plane[lf][u * 16 + ((cl + u) & 15)];
    size_t o = AIMAG + (size_t)rr * NF;
    if (dir_ok) out[o + fD] = v;
    if (mir_ok) out[o + fM] = -v;
  }
}

extern "C" void kernel_launch(void* const* d_in, const int* in_sizes, int n_in,
                              void* d_out, int out_size, void* d_ws, size_t ws_size,
                              hipStream_t stream) {
  const float* k1 = (const float*)d_in[0];
  const float* y  = (const float*)d_in[1];
  float* out = (float*)d_out;
  c32* spec1 = (c32*)d_out;   // kernel A output, 79.7 MB < 134 MB, overwritten later
  c32* spec  = (c32*)d_ws;    // kernel B output (f <= 33023 region), 76 MiB ws

  dim3 grid(16, NROWS);
  dim3 blk(256);

  fftA<<<grid, blk, 0, stream>>>(k1, y, spec1);
  fftB<<<grid, blk, 0, stream>>>(spec1, spec);

  init_out<<<1, 64, 0, stream>>>(out);
  invert_write<<<2049, blk, 0, stream>>>(spec, out);   // f = 0..32768
}